// Round 1
// baseline (437.211 us; speedup 1.0000x reference)
//
#include <hip/hip_runtime.h>

#define BB 8
#define HH 256
#define WW 512
#define CC 8
#define HW (HH * WW)          // 131072 = 2^17
#define NPIX (BB * HW)        // 1048576

// channels-last gate buffer index: ((b*HH + y)*WW + x)*CC + c

__global__ __launch_bounds__(256) void prep_kernel(
    const float* __restrict__ guidance,   // [B,8,H,W] NCHW
    const float* __restrict__ blur,       // [B,1,H,W]
    const float* __restrict__ sparse,     // [B,1,H,W]
    float* __restrict__ g_cl,             // [B,H,W,8]
    float* __restrict__ d0)               // [B,H,W]
{
    const int idx = blockIdx.x * 256 + threadIdx.x;   // pixel id in [0, NPIX)
    const int b = idx >> 17;
    const int p = idx & (HW - 1);
    const size_t gbase = ((size_t)b * CC) * HW + p;

    float4 v0, v1;
    v0.x = fabsf(guidance[gbase + 0 * HW]);
    v0.y = fabsf(guidance[gbase + 1 * HW]);
    v0.z = fabsf(guidance[gbase + 2 * HW]);
    v0.w = fabsf(guidance[gbase + 3 * HW]);
    v1.x = fabsf(guidance[gbase + 4 * HW]);
    v1.y = fabsf(guidance[gbase + 5 * HW]);
    v1.z = fabsf(guidance[gbase + 6 * HW]);
    v1.w = fabsf(guidance[gbase + 7 * HW]);

    float4* o = (float4*)(g_cl + (size_t)idx * CC);
    o[0] = v0;
    o[1] = v1;

    const float sp = sparse[idx];
    const float bl = blur[idx];
    d0[idx] = (sp > 0.0f) ? sp : bl;
}

__global__ __launch_bounds__(256) void wsum_kernel(
    const float* __restrict__ g_cl,       // [B,H,W,8]
    float* __restrict__ invw)             // [B,H,W,8]
{
    const int x = blockIdx.x * 64 + threadIdx.x;
    const int y = blockIdx.y * 4 + threadIdx.y;
    const int b = blockIdx.z;
    const int p = (b * HH + y) * WW + x;

    float s[8];
#pragma unroll
    for (int i = 0; i < 8; ++i) s[i] = 0.0f;

#pragma unroll
    for (int dy = -1; dy <= 1; ++dy) {
        const int yy = y + dy;
        if ((unsigned)yy >= HH) continue;
#pragma unroll
        for (int dx = -1; dx <= 1; ++dx) {
            const int xx = x + dx;
            if ((unsigned)xx >= WW) continue;
            const int q = (b * HH + yy) * WW + xx;
            const float4* gp = (const float4*)(g_cl + (size_t)q * CC);
            const float4 g0 = gp[0];
            const float4 g1 = gp[1];
            s[0] += g0.x; s[1] += g0.y; s[2] += g0.z; s[3] += g0.w;
            s[4] += g1.x; s[5] += g1.y; s[6] += g1.z; s[7] += g1.w;
        }
    }

    float4 w0, w1;
    w0.x = 1.0f / s[0]; w0.y = 1.0f / s[1]; w0.z = 1.0f / s[2]; w0.w = 1.0f / s[3];
    w1.x = 1.0f / s[4]; w1.y = 1.0f / s[5]; w1.z = 1.0f / s[6]; w1.w = 1.0f / s[7];
    float4* wp = (float4*)(invw + (size_t)p * CC);
    wp[0] = w0;
    wp[1] = w1;
}

__global__ __launch_bounds__(256) void iter_kernel(
    const float* __restrict__ g_cl,       // [B,H,W,8]
    const float* __restrict__ invw,       // [B,H,W,8]
    const float* __restrict__ d_in,       // [B,H,W]
    const float* __restrict__ sparse,     // [B,H,W]
    float* __restrict__ d_out)            // [B,H,W]
{
    const int x = blockIdx.x * 64 + threadIdx.x;
    const int y = blockIdx.y * 4 + threadIdx.y;
    const int b = blockIdx.z;
    const int p = (b * HH + y) * WW + x;

    float acc[8];
#pragma unroll
    for (int i = 0; i < 8; ++i) acc[i] = 0.0f;

#pragma unroll
    for (int dy = -1; dy <= 1; ++dy) {
        const int yy = y + dy;
        if ((unsigned)yy >= HH) continue;
#pragma unroll
        for (int dx = -1; dx <= 1; ++dx) {
            const int xx = x + dx;
            if ((unsigned)xx >= WW) continue;
            const int q = (b * HH + yy) * WW + xx;
            const float dv = d_in[q];
            const float4* gp = (const float4*)(g_cl + (size_t)q * CC);
            const float4 g0 = gp[0];
            const float4 g1 = gp[1];
            acc[0] = fmaf(g0.x, dv, acc[0]);
            acc[1] = fmaf(g0.y, dv, acc[1]);
            acc[2] = fmaf(g0.z, dv, acc[2]);
            acc[3] = fmaf(g0.w, dv, acc[3]);
            acc[4] = fmaf(g1.x, dv, acc[4]);
            acc[5] = fmaf(g1.y, dv, acc[5]);
            acc[6] = fmaf(g1.z, dv, acc[6]);
            acc[7] = fmaf(g1.w, dv, acc[7]);
        }
    }

    const float4* wp = (const float4*)(invw + (size_t)p * CC);
    const float4 w0 = wp[0];
    const float4 w1 = wp[1];

    float m = acc[0] * w0.x;
    m = fmaxf(m, acc[1] * w0.y);
    m = fmaxf(m, acc[2] * w0.z);
    m = fmaxf(m, acc[3] * w0.w);
    m = fmaxf(m, acc[4] * w1.x);
    m = fmaxf(m, acc[5] * w1.y);
    m = fmaxf(m, acc[6] * w1.z);
    m = fmaxf(m, acc[7] * w1.w);

    const float sp = sparse[p];
    d_out[p] = (sp > 0.0f) ? sp : m;
}

extern "C" void kernel_launch(void* const* d_in, const int* in_sizes, int n_in,
                              void* d_out, int out_size, void* d_ws, size_t ws_size,
                              hipStream_t stream) {
    const float* guidance = (const float*)d_in[0];
    const float* blur     = (const float*)d_in[1];
    const float* sparse   = (const float*)d_in[2];
    float* out = (float*)d_out;

    float* g_cl  = (float*)d_ws;                        // 33.55 MB
    float* invw  = g_cl + (size_t)NPIX * CC;            // 33.55 MB
    float* dbuf0 = invw + (size_t)NPIX * CC;            // 4 MB
    float* dbuf1 = dbuf0 + (size_t)NPIX;                // 4 MB

    prep_kernel<<<NPIX / 256, 256, 0, stream>>>(guidance, blur, sparse, g_cl, dbuf0);

    dim3 blk(64, 4, 1);
    dim3 grd(WW / 64, HH / 4, BB);
    wsum_kernel<<<grd, blk, 0, stream>>>(g_cl, invw);

    float* src = dbuf0;
    for (int it = 0; it < 16; ++it) {
        float* dst = (it == 15) ? out : ((it & 1) ? dbuf0 : dbuf1);
        iter_kernel<<<grd, blk, 0, stream>>>(g_cl, invw, src, sparse, dst);
        src = dst;
    }
}

// Round 2
// 309.349 us; speedup vs baseline: 1.4133x; 1.4133x over previous
//
#include <hip/hip_runtime.h>

#define BB 8
#define HH 256
#define WW 512
#define CC 8
#define HW (HH * WW)          // 131072 = 2^17
#define NPIX (BB * HW)        // 1048576

typedef _Float16 half8 __attribute__((ext_vector_type(8)));

// ---------------------------------------------------------------- prep ----
// g_cl: [B,H,W,8] fp16 = |guidance|; d0 = sparse>0 ? sparse : blur
__global__ __launch_bounds__(256) void prep_kernel(
    const float* __restrict__ guidance,   // [B,8,H,W] NCHW fp32
    const float* __restrict__ blur,       // [B,1,H,W]
    const float* __restrict__ sparse,     // [B,1,H,W]
    half8* __restrict__ g_cl,             // [B,H,W,8] fp16
    float* __restrict__ d0)               // [B,H,W]
{
    const int idx = blockIdx.x * 256 + threadIdx.x;
    const int b = idx >> 17;
    const int p = idx & (HW - 1);
    const size_t gbase = ((size_t)b * CC) * HW + p;

    half8 h;
#pragma unroll
    for (int c = 0; c < 8; ++c)
        h[c] = (_Float16)fabsf(guidance[gbase + (size_t)c * HW]);
    g_cl[idx] = h;

    const float sp = sparse[idx];
    d0[idx] = (sp > 0.0f) ? sp : blur[idx];
}

// ---------------------------------------------------------------- wsum ----
// invw = fp16( 1 / conv3x3_full(g_fp16) )  — computed FROM the rounded g so
// the g-rounding cancels between numerator and denominator in the iteration.
__global__ __launch_bounds__(256) void wsum_kernel(
    const half8* __restrict__ g_cl,       // [B,H,W,8] fp16
    half8* __restrict__ invw)             // [B,H,W,8] fp16
{
    const int x = blockIdx.x * 64 + threadIdx.x;
    const int y = blockIdx.y * 4 + threadIdx.y;
    const int b = blockIdx.z;
    const int p = (b * HH + y) * WW + x;

    float s[8];
#pragma unroll
    for (int i = 0; i < 8; ++i) s[i] = 0.0f;

#pragma unroll
    for (int dy = -1; dy <= 1; ++dy) {
        const int yy = y + dy;
        if ((unsigned)yy >= HH) continue;
#pragma unroll
        for (int dx = -1; dx <= 1; ++dx) {
            const int xx = x + dx;
            if ((unsigned)xx >= WW) continue;
            const half8 gh = g_cl[(b * HH + yy) * WW + xx];
#pragma unroll
            for (int c = 0; c < 8; ++c) s[c] += (float)gh[c];
        }
    }

    half8 w;
#pragma unroll
    for (int c = 0; c < 8; ++c) w[c] = (_Float16)(1.0f / s[c]);
    invw[p] = w;
}

// ---------------------------------------------------------------- iter ----
// Each thread produces 4 consecutive output rows at one x.
// rs[j][c] = sum_dx g[c][x+dx, y0-1+j] * d[x+dx, y0-1+j]   (j = 0..5)
// out[y0+i] = max_c (rs[i]+rs[i+1]+rs[i+2])[c] * invw[c]
__global__ __launch_bounds__(256) void iter_kernel(
    const half8* __restrict__ g_cl,       // [B,H,W,8] fp16
    const half8* __restrict__ invw,       // [B,H,W,8] fp16
    const float* __restrict__ d_in,       // [B,H,W]
    const float* __restrict__ sparse,     // [B,H,W]
    float* __restrict__ d_out)            // [B,H,W]
{
    const int x  = blockIdx.x * 64 + threadIdx.x;
    const int y0 = (blockIdx.y * 4 + threadIdx.y) * 4;   // 4 rows per thread
    const int b  = blockIdx.z;

    float rs[6][8];
#pragma unroll
    for (int j = 0; j < 6; ++j)
#pragma unroll
        for (int c = 0; c < 8; ++c) rs[j][c] = 0.0f;

#pragma unroll
    for (int j = 0; j < 6; ++j) {
        const int y = y0 - 1 + j;
        if ((unsigned)y >= HH) continue;
        const int rowbase = (b * HH + y) * WW;
#pragma unroll
        for (int dx = -1; dx <= 1; ++dx) {
            const int xx = x + dx;
            if ((unsigned)xx >= WW) continue;
            const int q = rowbase + xx;
            const float dv = d_in[q];
            const half8 gh = g_cl[q];
#pragma unroll
            for (int c = 0; c < 8; ++c)
                rs[j][c] = fmaf((float)gh[c], dv, rs[j][c]);
        }
    }

#pragma unroll
    for (int i = 0; i < 4; ++i) {
        const int p = (b * HH + (y0 + i)) * WW + x;
        const half8 wh = invw[p];
        float m = -3.4e38f;
#pragma unroll
        for (int c = 0; c < 8; ++c) {
            const float s = rs[i][c] + rs[i + 1][c] + rs[i + 2][c];
            m = fmaxf(m, s * (float)wh[c]);
        }
        const float sp = sparse[p];
        d_out[p] = (sp > 0.0f) ? sp : m;
    }
}

// -------------------------------------------------------------- launch ----
extern "C" void kernel_launch(void* const* d_in, const int* in_sizes, int n_in,
                              void* d_out, int out_size, void* d_ws, size_t ws_size,
                              hipStream_t stream) {
    const float* guidance = (const float*)d_in[0];
    const float* blur     = (const float*)d_in[1];
    const float* sparse   = (const float*)d_in[2];
    float* out = (float*)d_out;

    half8* g_cl  = (half8*)d_ws;                          // 16.78 MB
    half8* invw  = g_cl + (size_t)NPIX;                   // 16.78 MB
    float* dbuf0 = (float*)(invw + (size_t)NPIX);         // 4 MB
    float* dbuf1 = dbuf0 + (size_t)NPIX;                  // 4 MB

    prep_kernel<<<NPIX / 256, 256, 0, stream>>>(guidance, blur, sparse, g_cl, dbuf0);

    dim3 blk(64, 4, 1);
    dim3 grd_w(WW / 64, HH / 4, BB);
    wsum_kernel<<<grd_w, blk, 0, stream>>>(g_cl, invw);

    dim3 grd_i(WW / 64, HH / 16, BB);   // each block: 64 x-cols, 16 y-rows
    float* src = dbuf0;
    for (int it = 0; it < 16; ++it) {
        float* dst = (it == 15) ? out : ((it & 1) ? dbuf0 : dbuf1);
        iter_kernel<<<grd_i, blk, 0, stream>>>(g_cl, invw, src, sparse, dst);
        src = dst;
    }
}